// Round 14
// baseline (656.195 us; speedup 1.0000x reference)
//
#include <hip/hip_runtime.h>
#include <hip/hip_bf16.h>
#include <stdint.h>

#define Bb 32
#define Tt 2048
#define Dd 1024   // D_IN = D_H = D_OUT

typedef float    f32x4 __attribute__((ext_vector_type(4)));
typedef _Float16 f16x8 __attribute__((ext_vector_type(8)));
typedef uint32_t u32;

// ---- ws layout (bytes) ----
// 0        w2_ws  [32][1024] f32  (2 * s.W_a)          128K
// 131072   a_ws   [32][2048] f32                       256K
// 393216   UNION: e_part [8 ob][32 b][2048 t] f32 (2M, k_e->k_sm)
//                 cpart  [32 tc][32 b][1024] f32 (4M, k_c1->k_c2)
// 4587520  U_ts   tiled fp16 U^T (see k_ut)            2M
#define WS_A     131072
#define WS_EP    393216
#define WS_UT    4587520

__device__ __forceinline__ void gll16(const void* g, const void* lds) {
  __builtin_amdgcn_global_load_lds(
      (const __attribute__((address_space(1))) u32*)(uintptr_t)g,
      (__attribute__((address_space(3))) u32*)(uint32_t)(uintptr_t)lds,
      16, 0, 0);
}

// ---------------- kernel 1: w2[b][o] = 2 * sum_i s[b][i] * W[i][o] ----------------
__global__ __launch_bounds__(256) void k_ws(const float* __restrict__ s,
                                            const float* __restrict__ W,
                                            float* __restrict__ w2_ws) {
  const int b = blockIdx.x >> 2;
  const int o = (blockIdx.x & 3) * 256 + threadIdx.x;
  __shared__ float s_sh[Dd];
#pragma unroll
  for (int j = 0; j < 4; ++j)
    s_sh[threadIdx.x + 256 * j] = s[b * Dd + threadIdx.x + 256 * j];
  __syncthreads();
  float acc = 0.f;
#pragma unroll 8
  for (int i = 0; i < Dd; ++i) acc += s_sh[i] * W[(size_t)i * Dd + o];
  w2_ws[b * Dd + o] = 2.f * acc;
}

// ------- kernel 2: build U_ts, tile-major linear-lane layout -------
// Tile (ob 0..7, ks 0..15) = 16KB at (ob*16+ks)*16384; element (o_l, k_l):
// byte = (k_l>>5)*8192 + (o_l>>6)*4096 + ((o_l>>4)&3)*1024
//        + (((k_l>>3)&3)*16 + (o_l&15))*16 + (k_l&7)*2
__global__ __launch_bounds__(256) void k_ut(const float* __restrict__ U,
                                            uint8_t* __restrict__ U_ts) {
  const int i0 = (blockIdx.x >> 4) * 64;   // k-tile
  const int o0 = (blockIdx.x & 15) * 64;   // o-tile
  __shared__ float tile[64][65];           // [o_loc][k_loc]
  const int tx = threadIdx.x & 63;
  const int ty = threadIdx.x >> 6;
#pragma unroll
  for (int jj = 0; jj < 16; ++jj)
    tile[tx][ty + 4 * jj] = U[(size_t)(i0 + ty + 4 * jj) * Dd + o0 + tx];
  __syncthreads();
#pragma unroll
  for (int it = 0; it < 2; ++it) {
    const int g  = it * 256 + threadIdx.x;  // 0..511
    const int ol = g & 63;
    const int kg = g >> 6;                  // 0..7
    const int o  = o0 + ol;
    const int k  = i0 + kg * 8;
    f16x8 r;
#pragma unroll
    for (int m = 0; m < 8; ++m) r[m] = (_Float16)tile[ol][kg * 8 + m];
    const int ob  = o >> 7, ks = k >> 6;
    const int o_l = o & 127, k_l = k & 63;
    const size_t byte = ((size_t)(ob * 16 + ks) << 14)
                      + (size_t)((k_l >> 5) * 8192 + (o_l >> 6) * 4096
                      + ((o_l >> 4) & 3) * 1024
                      + (((k_l >> 3) & 3) * 16 + (o_l & 15)) * 16);
    *(f16x8*)(U_ts + byte) = r;
  }
}

// ---------------- kernel 3: fused GEMM, 128x128, single-barrier, B direct ----------------
// 4 waves (hw=o-half, tw=t-half), acc[4][4], BK=64 x 16 steps. LDS holds ONLY the
// A double-buffer (2x16KB) -> one barrier/step protects A. B gathered per-lane
// from h (L2-hot via XCD co-location) + in-reg cvt; br[16]+bf[8] fit (256,2)
// without spill (round-13 structure at spill-safe tile).
// vmcnt(16) at step top retires A(ks)'s 4 gll16, leaves B(ks)'s 16 in flight.
__global__ __launch_bounds__(256, 2) void k_e(const float* __restrict__ h,
                                              const uint8_t* __restrict__ U_ts,
                                              const float* __restrict__ w2_ws,
                                              const float* __restrict__ v_a,
                                              float* __restrict__ e_part) {
  const int blk = blockIdx.x;
  const int b   = blk >> 7;
  const int ob  = (blk >> 4) & 7;
  const int tb  = blk & 15;
  const int tid  = threadIdx.x;
  const int lane = tid & 63;
  const int w    = tid >> 6;
  const int hw   = w & 1;    // o-half
  const int tw   = w >> 1;   // t-half

  __shared__ __align__(16) uint8_t Al[2][16384];
  __shared__ float w_sh[128], v_sh[128], exch[128];

  if (tid < 128) {
    w_sh[tid] = w2_ws[b * Dd + ob * 128 + tid];
    v_sh[tid] = v_a[ob * 128 + tid];
  }

  // A staging: 16 segs of 1KB per step; wave w stages segs 4w..4w+3
  const uint8_t* Usrc = U_ts + ((size_t)(ob * 16) << 14)
                      + (size_t)(w * 4) * 1024 + (size_t)lane * 16;
  uint8_t* Ad0 = &Al[0][w * 4096];
  uint8_t* Ad1 = &Al[1][w * 4096];

  // B gather: lane reads h[t][k..k+7], t = tb*128+tw*64+m*16+(lane&15),
  // k = ks*64 + kk*32 + (lane>>4)*8
  const float* hb = h + ((size_t)(b * Tt + tb * 128 + tw * 64 + (lane & 15))) * Dd
                  + (lane >> 4) * 8;

  f32x4 acc[4][4] = {};
  f32x4 br[16];   // B(ks) f32 staging (64 VGPR)
  f16x8 bf[8];    // cvt'd fragments [kk*4+m]

  // A(0), B(0)
#pragma unroll
  for (int q = 0; q < 4; ++q) gll16(Usrc + q * 1024, Ad0 + q * 1024);
#pragma unroll
  for (int kk = 0; kk < 2; ++kk)
#pragma unroll
    for (int m = 0; m < 4; ++m) {
      const float* p = hb + (size_t)m * 16 * Dd + kk * 32;
      br[kk * 8 + m * 2]     = *(const f32x4*)p;
      br[kk * 8 + m * 2 + 1] = *(const f32x4*)(p + 4);
    }
  asm volatile("s_waitcnt lgkmcnt(0)" ::: "memory");  // w_sh/v_sh visible

#pragma unroll 1
  for (int ks = 0; ks < 16; ++ks) {
    const int p = ks & 1;
    asm volatile("s_waitcnt vmcnt(16)" ::: "memory");  // A(ks) landed (own segs)
    __builtin_amdgcn_sched_barrier(0);
    __builtin_amdgcn_s_barrier();                      // everyone's A(ks) landed
    __builtin_amdgcn_sched_barrier(0);
    if (ks < 15) {                      // stage A(ks+1) into other buffer
      const uint8_t* src = Usrc + ((size_t)(ks + 1) << 14);
      uint8_t* dst = p ? Ad0 : Ad1;
#pragma unroll
      for (int q = 0; q < 4; ++q) gll16(src + q * 1024, dst + q * 1024);
    }
    // cvt B(ks): register dep -> compiler waits the right vmcnt (B issued 1 step ago)
#pragma unroll
    for (int j = 0; j < 8; ++j) {
      f16x8 t;
#pragma unroll
      for (int m2 = 0; m2 < 4; ++m2) {
        t[m2]     = (_Float16)br[2 * j][m2];
        t[4 + m2] = (_Float16)br[2 * j + 1][m2];
      }
      bf[j] = t;
    }
    __builtin_amdgcn_sched_barrier(0);  // cvt before br overwrite
    if (ks < 15) {                      // issue B(ks+1) (stay in flight)
#pragma unroll
      for (int kk = 0; kk < 2; ++kk)
#pragma unroll
        for (int m = 0; m < 4; ++m) {
          const float* pp = hb + (size_t)m * 16 * Dd + (ks + 1) * 64 + kk * 32;
          br[kk * 8 + m * 2]     = *(const f32x4*)pp;
          br[kk * 8 + m * 2 + 1] = *(const f32x4*)(pp + 4);
        }
    }
    __builtin_amdgcn_sched_barrier(0);  // loads issued before MFMA block
    const uint8_t* Ab = &Al[p][0] + hw * 4096 + lane * 16;
#pragma unroll
    for (int kk = 0; kk < 2; ++kk) {
      f16x8 af[4];
#pragma unroll
      for (int n = 0; n < 4; ++n)
        af[n] = *(const f16x8*)(Ab + kk * 8192 + n * 1024);
#pragma unroll
      for (int m = 0; m < 4; ++m)
#pragma unroll
        for (int n = 0; n < 4; ++n)
          acc[m][n] = __builtin_amdgcn_mfma_f32_16x16x32_f16(af[n], bf[kk * 4 + m],
                                                             acc[m][n], 0, 0, 0);
    }
  }

  // ---- epilogue: tanh + v-weight + reduce over o ----
  float ep[4] = {0.f, 0.f, 0.f, 0.f};
#pragma unroll
  for (int m = 0; m < 4; ++m)
#pragma unroll
    for (int n = 0; n < 4; ++n)
#pragma unroll
      for (int r = 0; r < 4; ++r) {
        const int o_loc = hw * 64 + n * 16 + ((lane >> 4) << 2) + r;
        const float x = __builtin_fmaf(acc[m][n][r], 2.f, w_sh[o_loc]);
        ep[m] += v_sh[o_loc] * (1.f - 2.f / (__expf(x) + 1.f));
      }
#pragma unroll
  for (int m = 0; m < 4; ++m) {
    ep[m] += __shfl_xor(ep[m], 16, 64);
    ep[m] += __shfl_xor(ep[m], 32, 64);
  }
  __syncthreads();
  if (hw == 1 && lane < 16) {
#pragma unroll
    for (int m = 0; m < 4; ++m) exch[tw * 64 + m * 16 + lane] = ep[m];
  }
  __syncthreads();
  if (hw == 0 && lane < 16) {
#pragma unroll
    for (int m = 0; m < 4; ++m) {
      const int t_loc = tw * 64 + m * 16 + lane;
      e_part[((size_t)(ob * Bb + b)) * Tt + tb * 128 + t_loc] = ep[m] + exch[t_loc];
    }
  }
}

// ---------------- kernel 4: reduce 8 o-partials + softmax over T per b ----------------
__global__ __launch_bounds__(256) void k_sm(const float* __restrict__ e_part,
                                            float* __restrict__ a_ws) {
  const int b = blockIdx.x;
  const int lane = threadIdx.x & 63;
  const int wv = threadIdx.x >> 6;
  __shared__ float red[8];
  float ev[8];
  float m = -1e30f;
#pragma unroll
  for (int j = 0; j < 8; ++j) {
    const int t = threadIdx.x + 256 * j;
    float sv = 0.f;
#pragma unroll
    for (int o = 0; o < 8; ++o) sv += e_part[((size_t)(o * Bb + b)) * Tt + t];
    ev[j] = sv;
    m = fmaxf(m, sv);
  }
#pragma unroll
  for (int sft = 1; sft < 64; sft <<= 1) m = fmaxf(m, __shfl_xor(m, sft, 64));
  if (lane == 0) red[wv] = m;
  __syncthreads();
  m = fmaxf(fmaxf(red[0], red[1]), fmaxf(red[2], red[3]));
  float sum = 0.f;
#pragma unroll
  for (int j = 0; j < 8; ++j) { ev[j] = __expf(ev[j] - m); sum += ev[j]; }
#pragma unroll
  for (int sft = 1; sft < 64; sft <<= 1) sum += __shfl_xor(sum, sft, 64);
  if (lane == 0) red[4 + wv] = sum;
  __syncthreads();
  const float inv = 1.f / (red[4] + red[5] + red[6] + red[7]);
#pragma unroll
  for (int j = 0; j < 8; ++j) a_ws[b * Tt + threadIdx.x + 256 * j] = ev[j] * inv;
}

// ---------------- kernel 5a: partial c over 64-t chunks (deterministic) ----------------
__global__ __launch_bounds__(256) void k_c1(const float* __restrict__ h,
                                            const float* __restrict__ a_ws,
                                            float* __restrict__ cpart) {
  const int b  = blockIdx.x >> 5;
  const int tc = blockIdx.x & 31;
  const int t0 = tc << 6;
  __shared__ float a_sh[64];
  if (threadIdx.x < 64) a_sh[threadIdx.x] = a_ws[b * Tt + t0 + threadIdx.x];
  __syncthreads();
  f32x4 acc = {0.f, 0.f, 0.f, 0.f};
  const float* hb = h + ((size_t)b * Tt + t0) * Dd + threadIdx.x * 4;
#pragma unroll 4
  for (int t = 0; t < 64; ++t) {
    const f32x4 hv = *(const f32x4*)(hb + (size_t)t * Dd);
    acc += a_sh[t] * hv;
  }
  *(f32x4*)(cpart + ((size_t)(tc * 32 + b) << 10) + threadIdx.x * 4) = acc;
}

// ---------------- kernel 5b: reduce partials, store f32 ----------------
__global__ __launch_bounds__(256) void k_c2(const float* __restrict__ cpart,
                                            float* __restrict__ out) {
  const int gid = blockIdx.x * 256 + threadIdx.x;   // 0..32767
  const int b = gid >> 10;
  const int d = gid & 1023;
  float sv = 0.f;
#pragma unroll
  for (int tc = 0; tc < 32; ++tc) sv += cpart[((size_t)(tc * 32 + b) << 10) + d];
  out[gid] = sv;
}

extern "C" void kernel_launch(void* const* d_in, const int* in_sizes, int n_in,
                              void* d_out, int out_size, void* d_ws, size_t ws_size,
                              hipStream_t stream) {
  (void)in_sizes; (void)n_in; (void)out_size; (void)ws_size;
  const float* s  = (const float*)d_in[0];
  const float* h  = (const float*)d_in[1];
  const float* W  = (const float*)d_in[2];
  const float* U  = (const float*)d_in[3];
  const float* v  = (const float*)d_in[4];
  uint8_t* ws = (uint8_t*)d_ws;
  float*   w2_ws  = (float*)ws;
  float*   a_ws   = (float*)(ws + WS_A);
  float*   e_part = (float*)(ws + WS_EP);   // aliases cpart (sequential lifetimes)
  float*   cpart  = (float*)(ws + WS_EP);
  uint8_t* U_ts   = ws + WS_UT;

  k_ws<<<128, 256, 0, stream>>>(s, W, w2_ws);
  k_ut<<<256, 256, 0, stream>>>(U, U_ts);
  k_e <<<4096, 256, 0, stream>>>(h, U_ts, w2_ws, v, e_part);
  k_sm<<<Bb, 256, 0, stream>>>(e_part, a_ws);
  k_c1<<<1024, 256, 0, stream>>>(h, a_ws, cpart);
  k_c2<<<128, 256, 0, stream>>>(cpart, (float*)d_out);
}

// Round 15
// 395.827 us; speedup vs baseline: 1.6578x; 1.6578x over previous
//
#include <hip/hip_runtime.h>
#include <hip/hip_bf16.h>
#include <stdint.h>

#define Bb 32
#define Tt 2048
#define Dd 1024   // D_IN = D_H = D_OUT

typedef float    f32x4 __attribute__((ext_vector_type(4)));
typedef _Float16 f16x8 __attribute__((ext_vector_type(8)));
typedef uint32_t u32;

// ---- ws layout (bytes) ----
// 0        w2_ws  [32][1024] f32  (2 * s.W_a)          128K
// 131072   a_ws   [32][2048] f32                       256K
// 393216   UNION: e_part [4 obb][32 b][2048 t] f32 (1M, k_e->k_sm)
//                 cpart  [32 tc][32 b][1024] f32 (4M, k_c1->k_c2)
// 4587520  U_ts   tiled fp16 U^T (see k_ut)            2M
#define WS_A     131072
#define WS_EP    393216
#define WS_UT    4587520

__device__ __forceinline__ void gll16(const void* g, const void* lds) {
  __builtin_amdgcn_global_load_lds(
      (const __attribute__((address_space(1))) u32*)(uintptr_t)g,
      (__attribute__((address_space(3))) u32*)(uint32_t)(uintptr_t)lds,
      16, 0, 0);
}

// ---------------- kernel 1: w2[b][o] = 2 * sum_i s[b][i] * W[i][o] ----------------
__global__ __launch_bounds__(256) void k_ws(const float* __restrict__ s,
                                            const float* __restrict__ W,
                                            float* __restrict__ w2_ws) {
  const int b = blockIdx.x >> 2;
  const int o = (blockIdx.x & 3) * 256 + threadIdx.x;
  __shared__ float s_sh[Dd];
#pragma unroll
  for (int j = 0; j < 4; ++j)
    s_sh[threadIdx.x + 256 * j] = s[b * Dd + threadIdx.x + 256 * j];
  __syncthreads();
  float acc = 0.f;
#pragma unroll 8
  for (int i = 0; i < Dd; ++i) acc += s_sh[i] * W[(size_t)i * Dd + o];
  w2_ws[b * Dd + o] = 2.f * acc;
}

// ------- kernel 2: build U_ts, tile-major linear-lane layout (unchanged) -------
// Tile (ob 0..7, ks 0..15) = 16KB at (ob*16+ks)*16384; element (o_l, k_l):
// byte = (k_l>>5)*8192 + (o_l>>6)*4096 + ((o_l>>4)&3)*1024
//        + (((k_l>>3)&3)*16 + (o_l&15))*16 + (k_l&7)*2
__global__ __launch_bounds__(256) void k_ut(const float* __restrict__ U,
                                            uint8_t* __restrict__ U_ts) {
  const int i0 = (blockIdx.x >> 4) * 64;   // k-tile
  const int o0 = (blockIdx.x & 15) * 64;   // o-tile
  __shared__ float tile[64][65];           // [o_loc][k_loc]
  const int tx = threadIdx.x & 63;
  const int ty = threadIdx.x >> 6;
#pragma unroll
  for (int jj = 0; jj < 16; ++jj)
    tile[tx][ty + 4 * jj] = U[(size_t)(i0 + ty + 4 * jj) * Dd + o0 + tx];
  __syncthreads();
#pragma unroll
  for (int it = 0; it < 2; ++it) {
    const int g  = it * 256 + threadIdx.x;  // 0..511
    const int ol = g & 63;
    const int kg = g >> 6;                  // 0..7
    const int o  = o0 + ol;
    const int k  = i0 + kg * 8;
    f16x8 r;
#pragma unroll
    for (int m = 0; m < 8; ++m) r[m] = (_Float16)tile[ol][kg * 8 + m];
    const int ob  = o >> 7, ks = k >> 6;
    const int o_l = o & 127, k_l = k & 63;
    const size_t byte = ((size_t)(ob * 16 + ks) << 14)
                      + (size_t)((k_l >> 5) * 8192 + (o_l >> 6) * 4096
                      + ((o_l >> 4) & 3) * 1024
                      + (((k_l >> 3) & 3) * 16 + (o_l & 15)) * 16);
    *(f16x8*)(U_ts + byte) = r;
  }
}

// ---------------- kernel 3: barrier-free private-pipeline fused GEMM ----------------
// Block 64t x 256o, 4 waves; wave w owns o-quarter oq = obb*4+w (64 o), acc[4][4],
// 32 MFMA/step, BK=64 x 16 steps in 4 K-phases of 4 steps.
// B (h rows) in registers: hreg[32] f16x8 = wave's 64t x 256k fp16, refreshed per
// phase via coalesced f32 LDS staging (+t XOR swizzle; scatter hits LDS, not TA).
// A is wave-PRIVATE: wave gll16-stages only its own 8KB/step (dbuf in its own LDS
// region) -> steady-state K-steps have NO barriers; ordering via own vmcnt(8)
// and af-read->lgkmcnt(0)->DMA for WAR. 3 barriers per phase (12 total).
__global__ __launch_bounds__(256, 2) void k_e(const float* __restrict__ h,
                                              const uint8_t* __restrict__ U_ts,
                                              const float* __restrict__ w2_ws,
                                              const float* __restrict__ v_a,
                                              float* __restrict__ e_part) {
  const int blk = blockIdx.x;
  const int b   = blk >> 7;
  const int obb = (blk >> 5) & 3;   // 256-o block
  const int tt  = blk & 31;         // 64-t tile
  const int tid  = threadIdx.x;
  const int lane = tid & 63;
  const int w    = tid >> 6;

  __shared__ __align__(16) uint8_t Sbuf[65536];  // phase-stage f32 AND per-wave A dbufs
  __shared__ float w_sh[256], v_sh[256], exch[256];

  w_sh[tid] = w2_ws[b * Dd + obb * 256 + tid];
  v_sh[tid] = v_a[obb * 256 + tid];

  // A addressing: oq's 8KB/step = segs [kk][half][q] of the 128-o tile
  const int oq   = obb * 4 + w;
  const int ob   = oq >> 1;
  const int half = oq & 1;
  const uint8_t* Utile = U_ts + ((size_t)(ob * 16) << 14) + half * 4096 + (size_t)lane * 16;
  uint8_t* A0 = Sbuf + w * 16384;
  uint8_t* A1 = A0 + 8192;

  const float* hsrc = h + (size_t)(b * Tt + tt * 64) * Dd;

  f32x4 acc[4][4] = {};
  f16x8 hreg[32];   // [u*4+m], u = k32-unit within phase, m = t-subtile

#pragma unroll 1
  for (int kp = 0; kp < 4; ++kp) {
    __syncthreads();   // all waves' A-DMAs retired (own vmcnt(0) at prev st3) + reads done
    // ---- stage h chunk kp: 64t x 256k f32, coalesced, +t XOR swizzle ----
#pragma unroll 8
    for (int j = 0; j < 16; ++j) {
      const int q = tid + 256 * j;          // 0..4095 f32x4
      const int t = q >> 6;
      const int sslot = q & 63;
      const f32x4 val = *(const f32x4*)(hsrc + (size_t)t * Dd + kp * 256 + sslot * 4);
      *(f32x4*)(Sbuf + t * 1024 + ((sslot ^ (t & 7)) << 4)) = val;
    }
    __syncthreads();   // stage visible
    // ---- hreg fill: scattered LDS reads + cvt ----
#pragma unroll
    for (int u = 0; u < 8; ++u)
#pragma unroll
      for (int m = 0; m < 4; ++m) {
        const int t  = m * 16 + (lane & 15);
        const int s0 = u * 8 + (lane >> 4) * 2;
        const f32x4 lo = *(const f32x4*)(Sbuf + t * 1024 + (((s0)     ^ (t & 7)) << 4));
        const f32x4 hi = *(const f32x4*)(Sbuf + t * 1024 + (((s0 + 1) ^ (t & 7)) << 4));
        f16x8 r;
        r[0] = (_Float16)lo[0]; r[1] = (_Float16)lo[1];
        r[2] = (_Float16)lo[2]; r[3] = (_Float16)lo[3];
        r[4] = (_Float16)hi[0]; r[5] = (_Float16)hi[1];
        r[6] = (_Float16)hi[2]; r[7] = (_Float16)hi[3];
        hreg[u * 4 + m] = r;
      }
    __syncthreads();   // all hreg reads done before A-DMA overwrites Sbuf
    // ---- prime A pipeline: 2 steps ahead (own 16 gll16 in flight) ----
    {
      const int ks0 = kp * 4;
#pragma unroll
      for (int kk = 0; kk < 2; ++kk)
#pragma unroll
        for (int q = 0; q < 4; ++q) {
          gll16(Utile + ((size_t)ks0 << 14) + kk * 8192 + q * 1024,
                A0 + kk * 4096 + q * 1024);
        }
#pragma unroll
      for (int kk = 0; kk < 2; ++kk)
#pragma unroll
        for (int q = 0; q < 4; ++q) {
          gll16(Utile + ((size_t)(ks0 + 1) << 14) + kk * 8192 + q * 1024,
                A1 + kk * 4096 + q * 1024);
        }
    }
    // ---- 4 barrier-free steps ----
#pragma unroll
    for (int st = 0; st < 4; ++st) {
      if (st < 3) { asm volatile("s_waitcnt vmcnt(8)" ::: "memory"); }
      else        { asm volatile("s_waitcnt vmcnt(0)" ::: "memory"); }
      __builtin_amdgcn_sched_barrier(0);
      const uint8_t* Ab = (st & 1) ? A1 : A0;
      f16x8 af[2][4];
#pragma unroll
      for (int kk = 0; kk < 2; ++kk)
#pragma unroll
        for (int n = 0; n < 4; ++n)
          af[kk][n] = *(const f16x8*)(Ab + kk * 4096 + n * 1024 + lane * 16);
      asm volatile("s_waitcnt lgkmcnt(0)" ::: "memory");   // af in regs
      __builtin_amdgcn_sched_barrier(0);
      if (st < 2) {   // stage A(ks+2) into the buffer just consumed
        const int ksn = kp * 4 + st + 2;
        uint8_t* dst = (st & 1) ? A1 : A0;
#pragma unroll
        for (int kk = 0; kk < 2; ++kk)
#pragma unroll
          for (int q = 0; q < 4; ++q)
            gll16(Utile + ((size_t)ksn << 14) + kk * 8192 + q * 1024,
                  dst + kk * 4096 + q * 1024);
      }
      __builtin_amdgcn_sched_barrier(0);
#pragma unroll
      for (int kk = 0; kk < 2; ++kk)
#pragma unroll
        for (int m = 0; m < 4; ++m)
#pragma unroll
          for (int n = 0; n < 4; ++n)
            acc[m][n] = __builtin_amdgcn_mfma_f32_16x16x32_f16(
                af[kk][n], hreg[(st * 2 + kk) * 4 + m], acc[m][n], 0, 0, 0);
    }
  }

  // ---- epilogue: tanh + v-weight + reduce over o (wave-private 64 o) ----
  float ep[4] = {0.f, 0.f, 0.f, 0.f};
#pragma unroll
  for (int m = 0; m < 4; ++m)
#pragma unroll
    for (int n = 0; n < 4; ++n)
#pragma unroll
      for (int r = 0; r < 4; ++r) {
        const int o_loc = w * 64 + n * 16 + ((lane >> 4) << 2) + r;
        const float x = __builtin_fmaf(acc[m][n][r], 2.f, w_sh[o_loc]);
        ep[m] += v_sh[o_loc] * (1.f - 2.f / (__expf(x) + 1.f));
      }
#pragma unroll
  for (int m = 0; m < 4; ++m) {
    ep[m] += __shfl_xor(ep[m], 16, 64);
    ep[m] += __shfl_xor(ep[m], 32, 64);
  }
  __syncthreads();
  if (lane < 16) {
#pragma unroll
    for (int m = 0; m < 4; ++m) exch[w * 64 + m * 16 + lane] = ep[m];
  }
  __syncthreads();
  if (tid < 64) {
    const float sv = exch[tid] + exch[64 + tid] + exch[128 + tid] + exch[192 + tid];
    e_part[((size_t)(obb * Bb + b)) * Tt + tt * 64 + tid] = sv;
  }
}

// ---------------- kernel 4: reduce 4 o-partials + softmax over T per b ----------------
__global__ __launch_bounds__(256) void k_sm(const float* __restrict__ e_part,
                                            float* __restrict__ a_ws) {
  const int b = blockIdx.x;
  const int lane = threadIdx.x & 63;
  const int wv = threadIdx.x >> 6;
  __shared__ float red[8];
  float ev[8];
  float m = -1e30f;
#pragma unroll
  for (int j = 0; j < 8; ++j) {
    const int t = threadIdx.x + 256 * j;
    float sv = 0.f;
#pragma unroll
    for (int o = 0; o < 4; ++o) sv += e_part[((size_t)(o * Bb + b)) * Tt + t];
    ev[j] = sv;
    m = fmaxf(m, sv);
  }
#pragma unroll
  for (int sft = 1; sft < 64; sft <<= 1) m = fmaxf(m, __shfl_xor(m, sft, 64));
  if (lane == 0) red[wv] = m;
  __syncthreads();
  m = fmaxf(fmaxf(red[0], red[1]), fmaxf(red[2], red[3]));
  float sum = 0.f;
#pragma unroll
  for (int j = 0; j < 8; ++j) { ev[j] = __expf(ev[j] - m); sum += ev[j]; }
#pragma unroll
  for (int sft = 1; sft < 64; sft <<= 1) sum += __shfl_xor(sum, sft, 64);
  if (lane == 0) red[4 + wv] = sum;
  __syncthreads();
  const float inv = 1.f / (red[4] + red[5] + red[6] + red[7]);
#pragma unroll
  for (int j = 0; j < 8; ++j) a_ws[b * Tt + threadIdx.x + 256 * j] = ev[j] * inv;
}

// ---------------- kernel 5a: partial c over 64-t chunks (deterministic) ----------------
__global__ __launch_bounds__(256) void k_c1(const float* __restrict__ h,
                                            const float* __restrict__ a_ws,
                                            float* __restrict__ cpart) {
  const int b  = blockIdx.x >> 5;
  const int tc = blockIdx.x & 31;
  const int t0 = tc << 6;
  __shared__ float a_sh[64];
  if (threadIdx.x < 64) a_sh[threadIdx.x] = a_ws[b * Tt + t0 + threadIdx.x];
  __syncthreads();
  f32x4 acc = {0.f, 0.f, 0.f, 0.f};
  const float* hb = h + ((size_t)b * Tt + t0) * Dd + threadIdx.x * 4;
#pragma unroll 4
  for (int t = 0; t < 64; ++t) {
    const f32x4 hv = *(const f32x4*)(hb + (size_t)t * Dd);
    acc += a_sh[t] * hv;
  }
  *(f32x4*)(cpart + ((size_t)(tc * 32 + b) << 10) + threadIdx.x * 4) = acc;
}

// ---------------- kernel 5b: reduce partials, store f32 ----------------
__global__ __launch_bounds__(256) void k_c2(const float* __restrict__ cpart,
                                            float* __restrict__ out) {
  const int gid = blockIdx.x * 256 + threadIdx.x;   // 0..32767
  const int b = gid >> 10;
  const int d = gid & 1023;
  float sv = 0.f;
#pragma unroll
  for (int tc = 0; tc < 32; ++tc) sv += cpart[((size_t)(tc * 32 + b) << 10) + d];
  out[gid] = sv;
}

extern "C" void kernel_launch(void* const* d_in, const int* in_sizes, int n_in,
                              void* d_out, int out_size, void* d_ws, size_t ws_size,
                              hipStream_t stream) {
  (void)in_sizes; (void)n_in; (void)out_size; (void)ws_size;
  const float* s  = (const float*)d_in[0];
  const float* h  = (const float*)d_in[1];
  const float* W  = (const float*)d_in[2];
  const float* U  = (const float*)d_in[3];
  const float* v  = (const float*)d_in[4];
  uint8_t* ws = (uint8_t*)d_ws;
  float*   w2_ws  = (float*)ws;
  float*   a_ws   = (float*)(ws + WS_A);
  float*   e_part = (float*)(ws + WS_EP);   // aliases cpart (sequential lifetimes)
  float*   cpart  = (float*)(ws + WS_EP);
  uint8_t* U_ts   = ws + WS_UT;

  k_ws<<<128, 256, 0, stream>>>(s, W, w2_ws);
  k_ut<<<256, 256, 0, stream>>>(U, U_ts);
  k_e <<<4096, 256, 0, stream>>>(h, U_ts, w2_ws, v, e_part);
  k_sm<<<Bb, 256, 0, stream>>>(e_part, a_ws);
  k_c1<<<1024, 256, 0, stream>>>(h, a_ws, cpart);
  k_c2<<<128, 256, 0, stream>>>(cpart, (float*)d_out);
}

// Round 16
// 282.982 us; speedup vs baseline: 2.3189x; 1.3988x over previous
//
#include <hip/hip_runtime.h>
#include <hip/hip_bf16.h>
#include <stdint.h>

#define Bb 32
#define Tt 2048
#define Dd 1024   // D_IN = D_H = D_OUT

typedef float    f32x4 __attribute__((ext_vector_type(4)));
typedef _Float16 f16x8 __attribute__((ext_vector_type(8)));
typedef uint32_t u32;

// ---- ws layout (bytes) ----
// 0        w2_ws  [32][1024] f32  (2 * s.W_a)          128K
// 131072   a_ws   [32][2048] f32                       256K
// 393216   UNION: e_part [4 obb][32 b][2048 t] f32 (1M, k_e->k_sm)
//                 cpart  [32 tc][32 b][1024] f32 (4M, k_c1->k_c2)
// 4587520  U_ts   tiled fp16 U^T (see k_ut)            2M
#define WS_A     131072
#define WS_EP    393216
#define WS_UT    4587520

__device__ __forceinline__ void gll16(const void* g, const void* lds) {
  __builtin_amdgcn_global_load_lds(
      (const __attribute__((address_space(1))) u32*)(uintptr_t)g,
      (__attribute__((address_space(3))) u32*)(uint32_t)(uintptr_t)lds,
      16, 0, 0);
}

// ---------------- kernel 1: w2[b][o] = 2 * sum_i s[b][i] * W[i][o] ----------------
__global__ __launch_bounds__(256) void k_ws(const float* __restrict__ s,
                                            const float* __restrict__ W,
                                            float* __restrict__ w2_ws) {
  const int b = blockIdx.x >> 2;
  const int o = (blockIdx.x & 3) * 256 + threadIdx.x;
  __shared__ float s_sh[Dd];
#pragma unroll
  for (int j = 0; j < 4; ++j)
    s_sh[threadIdx.x + 256 * j] = s[b * Dd + threadIdx.x + 256 * j];
  __syncthreads();
  float acc = 0.f;
#pragma unroll 8
  for (int i = 0; i < Dd; ++i) acc += s_sh[i] * W[(size_t)i * Dd + o];
  w2_ws[b * Dd + o] = 2.f * acc;
}

// ------- kernel 2: build U_ts, tile-major linear-lane layout (unchanged) -------
// Tile (ob 0..7, ks 0..15) = 16KB at (ob*16+ks)*16384; element (o_l, k_l):
// byte = (k_l>>5)*8192 + (o_l>>6)*4096 + ((o_l>>4)&3)*1024
//        + (((k_l>>3)&3)*16 + (o_l&15))*16 + (k_l&7)*2
__global__ __launch_bounds__(256) void k_ut(const float* __restrict__ U,
                                            uint8_t* __restrict__ U_ts) {
  const int i0 = (blockIdx.x >> 4) * 64;   // k-tile
  const int o0 = (blockIdx.x & 15) * 64;   // o-tile
  __shared__ float tile[64][65];           // [o_loc][k_loc]
  const int tx = threadIdx.x & 63;
  const int ty = threadIdx.x >> 6;
#pragma unroll
  for (int jj = 0; jj < 16; ++jj)
    tile[tx][ty + 4 * jj] = U[(size_t)(i0 + ty + 4 * jj) * Dd + o0 + tx];
  __syncthreads();
#pragma unroll
  for (int it = 0; it < 2; ++it) {
    const int g  = it * 256 + threadIdx.x;  // 0..511
    const int ol = g & 63;
    const int kg = g >> 6;                  // 0..7
    const int o  = o0 + ol;
    const int k  = i0 + kg * 8;
    f16x8 r;
#pragma unroll
    for (int m = 0; m < 8; ++m) r[m] = (_Float16)tile[ol][kg * 8 + m];
    const int ob  = o >> 7, ks = k >> 6;
    const int o_l = o & 127, k_l = k & 63;
    const size_t byte = ((size_t)(ob * 16 + ks) << 14)
                      + (size_t)((k_l >> 5) * 8192 + (o_l >> 6) * 4096
                      + ((o_l >> 4) & 3) * 1024
                      + (((k_l >> 3) & 3) * 16 + (o_l & 15)) * 16);
    *(f16x8*)(U_ts + byte) = r;
  }
}

// ---------------- kernel 3: fused GEMM, 128t x 256o, 512 thr, 8 waves ----------------
// Waves: tw = w>>2 (t-half 64), ow = w&3 (o-quarter 64); per wave acc[4][4],
// 32 MFMA/step -> 256 MFMA per block-step (2x R11 at same B-staging cost).
// m97-style 2-barrier step: b1; stage A(ks) via 4 gll16/thread (2 U_ts tiles);
// ds_write pk (B(ks) fp16, R11 XOR swizzle); b2 (drains); issue br(ks+1);
// 16 ds_read + 32 MFMA; cvt br->pk. LDS 50KB single-buffered -> 3 blocks/CU.
__global__ __launch_bounds__(512, 3) void k_e(const float* __restrict__ h,
                                              const uint8_t* __restrict__ U_ts,
                                              const float* __restrict__ w2_ws,
                                              const float* __restrict__ v_a,
                                              float* __restrict__ e_part) {
  const int blk = blockIdx.x;
  const int b   = blk >> 6;
  const int obb = (blk >> 4) & 3;   // 256-o block
  const int tb  = blk & 15;         // 128-t tile (fastest -> obb-sharers same XCD)
  const int tid  = threadIdx.x;
  const int lane = tid & 63;
  const int w    = tid >> 6;   // 0..7
  const int tw   = w >> 2;     // t-half
  const int ow   = w & 3;      // o-quarter

  __shared__ __align__(16) uint8_t Al[32768];
  __shared__ __align__(16) uint8_t Bl[16384];
  __shared__ float exch[512];

  // ---- A staging addressing: 4 gll16/thread; q -> tile (obb*2 + (q>>1)) ----
  // src unit = (q&1)*512 + w*64 + lane (16B units); dst = Al + q*8192 + w*1024.
  const uint8_t* Asrc[4];
#pragma unroll
  for (int q = 0; q < 4; ++q)
    Asrc[q] = U_ts + ((size_t)((obb * 2 + (q >> 1)) * 16) << 14)
            + (size_t)(((q & 1) * 512 + w * 64 + lane) * 16);

  // ---- B addressing: 2 units/thread: u = j*512+tid -> t_l = u>>3, kg = u&7 ----
  const float* hb[2];
  int baddr[2];
#pragma unroll
  for (int j = 0; j < 2; ++j) {
    const int u   = j * 512 + tid;
    const int t_l = u >> 3;
    const int kg  = u & 7;
    hb[j] = h + ((size_t)(b * Tt + tb * 128 + t_l)) * Dd + kg * 8;
    const int kk  = kg >> 2;
    const int klo = kg & 3;
    baddr[j] = kk * 8192 + (t_l >> 6) * 4096 + ((t_l >> 4) & 3) * 1024
             + (klo * 16 + ((t_l & 15) ^ kg)) * 16;
  }

  // ---- fragment read offsets ----
  const int aoff = (ow >> 1) * 16384 + (ow & 1) * 4096 + lane * 16;  // +kk*8192+n*1024
  const int klo_r = lane >> 4;
  const int rs0 = (klo_r * 16 + ((lane & 15) ^ klo_r)) * 16;
  const int rs1 = (klo_r * 16 + ((lane & 15) ^ klo_r ^ 4)) * 16;
  const int boff = tw * 4096;                                        // +kk*8192+m*1024+rs

  f32x4 acc[4][4] = {};   // [m = t-sub][n = o-sub]
  f32x4 br[4];
  f16x8 pk[2];

  // ---- prologue: B(0) -> br -> pk ----
#pragma unroll
  for (int j = 0; j < 2; ++j) {
    br[2 * j]     = *(const f32x4*)(hb[j]);
    br[2 * j + 1] = *(const f32x4*)(hb[j] + 4);
  }
#pragma unroll
  for (int j = 0; j < 2; ++j) {
    f16x8 t;
#pragma unroll
    for (int m2 = 0; m2 < 4; ++m2) {
      t[m2]     = (_Float16)br[2 * j][m2];
      t[4 + m2] = (_Float16)br[2 * j + 1][m2];
    }
    pk[j] = t;
  }

#pragma unroll 1
  for (int ks = 0; ks < 16; ++ks) {
    __syncthreads();                       // prev step's frag reads done; LDS free
    // stage A(ks): 4 gll16 (dst wave-uniform + lane*16)
#pragma unroll
    for (int q = 0; q < 4; ++q)
      gll16(Asrc[q] + ((size_t)ks << 14), Al + q * 8192 + w * 1024);
    // write B(ks) fp16 (swizzled, conflict-free)
#pragma unroll
    for (int j = 0; j < 2; ++j) *(f16x8*)(Bl + baddr[j]) = pk[j];
    __syncthreads();                       // A-DMA + B-writes visible (drain)
    // issue B(ks+1) loads (hidden under MFMA; ks=15 wraps harmlessly)
    const int kso = (ks < 15 ? ks + 1 : 0) * 64;
#pragma unroll
    for (int j = 0; j < 2; ++j) {
      br[2 * j]     = *(const f32x4*)(hb[j] + kso);
      br[2 * j + 1] = *(const f32x4*)(hb[j] + kso + 4);
    }
    // MFMA: 2 kk-slices x 16
#pragma unroll
    for (int kk = 0; kk < 2; ++kk) {
      f16x8 af[4], bf[4];
#pragma unroll
      for (int n = 0; n < 4; ++n)
        af[n] = *(const f16x8*)(Al + aoff + kk * 8192 + n * 1024);
#pragma unroll
      for (int m = 0; m < 4; ++m)
        bf[m] = *(const f16x8*)(Bl + boff + kk * 8192 + m * 1024 + (kk ? rs1 : rs0));
#pragma unroll
      for (int m = 0; m < 4; ++m)
#pragma unroll
        for (int n = 0; n < 4; ++n)
          acc[m][n] = __builtin_amdgcn_mfma_f32_16x16x32_f16(af[n], bf[m],
                                                             acc[m][n], 0, 0, 0);
    }
    // cvt B(ks+1) -> pk (reg-dep waits loads; hides under MFMA tail)
#pragma unroll
    for (int j = 0; j < 2; ++j) {
      f16x8 t;
#pragma unroll
      for (int m2 = 0; m2 < 4; ++m2) {
        t[m2]     = (_Float16)br[2 * j][m2];
        t[4 + m2] = (_Float16)br[2 * j + 1][m2];
      }
      pk[j] = t;
    }
  }

  // ---- epilogue: tanh + v-weight + reduce over o ----
  const float* wbase = w2_ws + b * Dd + obb * 256;
  const float* vbase = v_a + obb * 256;
  float ep[4] = {0.f, 0.f, 0.f, 0.f};
#pragma unroll
  for (int n = 0; n < 4; ++n) {
    const int og = ow * 64 + n * 16 + ((lane >> 4) << 2);
    const f32x4 w4 = *(const f32x4*)(wbase + og);
    const f32x4 v4 = *(const f32x4*)(vbase + og);
#pragma unroll
    for (int m = 0; m < 4; ++m)
#pragma unroll
      for (int r = 0; r < 4; ++r) {
        const float x = __builtin_fmaf(acc[m][n][r], 2.f, w4[r]);
        ep[m] += v4[r] * (1.f - 2.f / (__expf(x) + 1.f));
      }
  }
#pragma unroll
  for (int m = 0; m < 4; ++m) {
    ep[m] += __shfl_xor(ep[m], 16, 64);
    ep[m] += __shfl_xor(ep[m], 32, 64);
  }
  __syncthreads();
  if (lane < 16) {
#pragma unroll
    for (int m = 0; m < 4; ++m)
      exch[ow * 128 + tw * 64 + m * 16 + lane] = ep[m];
  }
  __syncthreads();
  if (tid < 128) {
    const float sv = exch[tid] + exch[128 + tid] + exch[256 + tid] + exch[384 + tid];
    e_part[((size_t)(obb * Bb + b)) * Tt + tb * 128 + tid] = sv;
  }
}

// ---------------- kernel 4: reduce 4 o-partials + softmax over T per b ----------------
__global__ __launch_bounds__(256) void k_sm(const float* __restrict__ e_part,
                                            float* __restrict__ a_ws) {
  const int b = blockIdx.x;
  const int lane = threadIdx.x & 63;
  const int wv = threadIdx.x >> 6;
  __shared__ float red[8];
  float ev[8];
  float m = -1e30f;
#pragma unroll
  for (int j = 0; j < 8; ++j) {
    const int t = threadIdx.x + 256 * j;
    float sv = 0.f;
#pragma unroll
    for (int o = 0; o < 4; ++o) sv += e_part[((size_t)(o * Bb + b)) * Tt + t];
    ev[j] = sv;
    m = fmaxf(m, sv);
  }
#pragma unroll
  for (int sft = 1; sft < 64; sft <<= 1) m = fmaxf(m, __shfl_xor(m, sft, 64));
  if (lane == 0) red[wv] = m;
  __syncthreads();
  m = fmaxf(fmaxf(red[0], red[1]), fmaxf(red[2], red[3]));
  float sum = 0.f;
#pragma unroll
  for (int j = 0; j < 8; ++j) { ev[j] = __expf(ev[j] - m); sum += ev[j]; }
#pragma unroll
  for (int sft = 1; sft < 64; sft <<= 1) sum += __shfl_xor(sum, sft, 64);
  if (lane == 0) red[4 + wv] = sum;
  __syncthreads();
  const float inv = 1.f / (red[4] + red[5] + red[6] + red[7]);
#pragma unroll
  for (int j = 0; j < 8; ++j) a_ws[b * Tt + threadIdx.x + 256 * j] = ev[j] * inv;
}

// ---------------- kernel 5a: partial c over 64-t chunks (deterministic) ----------------
__global__ __launch_bounds__(256) void k_c1(const float* __restrict__ h,
                                            const float* __restrict__ a_ws,
                                            float* __restrict__ cpart) {
  const int b  = blockIdx.x >> 5;
  const int tc = blockIdx.x & 31;
  const int t0 = tc << 6;
  __shared__ float a_sh[64];
  if (threadIdx.x < 64) a_sh[threadIdx.x] = a_ws[b * Tt + t0 + threadIdx.x];
  __syncthreads();
  f32x4 acc = {0.f, 0.f, 0.f, 0.f};
  const float* hb = h + ((size_t)b * Tt + t0) * Dd + threadIdx.x * 4;
#pragma unroll 4
  for (int t = 0; t < 64; ++t) {
    const f32x4 hv = *(const f32x4*)(hb + (size_t)t * Dd);
    acc += a_sh[t] * hv;
  }
  *(f32x4*)(cpart + ((size_t)(tc * 32 + b) << 10) + threadIdx.x * 4) = acc;
}

// ---------------- kernel 5b: reduce partials, store f32 ----------------
__global__ __launch_bounds__(256) void k_c2(const float* __restrict__ cpart,
                                            float* __restrict__ out) {
  const int gid = blockIdx.x * 256 + threadIdx.x;   // 0..32767
  const int b = gid >> 10;
  const int d = gid & 1023;
  float sv = 0.f;
#pragma unroll
  for (int tc = 0; tc < 32; ++tc) sv += cpart[((size_t)(tc * 32 + b) << 10) + d];
  out[gid] = sv;
}

extern "C" void kernel_launch(void* const* d_in, const int* in_sizes, int n_in,
                              void* d_out, int out_size, void* d_ws, size_t ws_size,
                              hipStream_t stream) {
  (void)in_sizes; (void)n_in; (void)out_size; (void)ws_size;
  const float* s  = (const float*)d_in[0];
  const float* h  = (const float*)d_in[1];
  const float* W  = (const float*)d_in[2];
  const float* U  = (const float*)d_in[3];
  const float* v  = (const float*)d_in[4];
  uint8_t* ws = (uint8_t*)d_ws;
  float*   w2_ws  = (float*)ws;
  float*   a_ws   = (float*)(ws + WS_A);
  float*   e_part = (float*)(ws + WS_EP);   // aliases cpart (sequential lifetimes)
  float*   cpart  = (float*)(ws + WS_EP);
  uint8_t* U_ts   = ws + WS_UT;

  k_ws<<<128, 256, 0, stream>>>(s, W, w2_ws);
  k_ut<<<256, 256, 0, stream>>>(U, U_ts);
  k_e <<<2048, 512, 0, stream>>>(h, U_ts, w2_ws, v, e_part);
  k_sm<<<Bb, 256, 0, stream>>>(e_part, a_ws);
  k_c1<<<1024, 256, 0, stream>>>(h, a_ws, cpart);
  k_c2<<<128, 256, 0, stream>>>(cpart, (float*)d_out);
}